// Round 1
// baseline (1659.923 us; speedup 1.0000x reference)
//
#include <hip/hip_runtime.h>
#include <hip/hip_bf16.h>

#define N_NODES 50000
#define N_EDGES 500000
#define HEADS 8
#define HID 64
#define HD 512   // HEADS*HID
#define NCLS 10

// ---------------------------------------------------------------------------
// fc projection: h[n,j] = feat_type(n) @ fcW + fcb   (j<64)
// ---------------------------------------------------------------------------
__global__ void fc_kernel(const float* __restrict__ f0, const float* __restrict__ f1,
                          const float* __restrict__ w0, const float* __restrict__ b0,
                          const float* __restrict__ w1, const float* __restrict__ b1,
                          float* __restrict__ h) {
    int t = blockIdx.x * blockDim.x + threadIdx.x;
    if (t >= N_NODES * 64) return;
    int n = t >> 6, j = t & 63;
    const float* f; const float* w; const float* b; int K;
    if (n < 30000) { f = f0 + (size_t)n * 256; w = w0; b = b0; K = 256; }
    else           { f = f1 + (size_t)(n - 30000) * 128; w = w1; b = b1; K = 128; }
    float acc = b[j];
    for (int k = 0; k < K; k++) acc += f[k] * w[k * 64 + j];
    h[t] = acc;
}

// ---------------------------------------------------------------------------
// CSR build: count -> scan -> scatter
// ---------------------------------------------------------------------------
__global__ void count_kernel(const int* __restrict__ dst, int* __restrict__ cnt) {
    int t = blockIdx.x * blockDim.x + threadIdx.x;
    if (t < N_EDGES) atomicAdd(&cnt[dst[t]], 1);
}

__global__ void scan_kernel(const int* __restrict__ counts, int* __restrict__ row_ptr,
                            int* __restrict__ cursor) {
    __shared__ int part[1024];
    const int n = N_NODES;
    int tid = threadIdx.x;
    const int C = (n + 1023) / 1024;
    int s = 0;
    for (int i = 0; i < C; i++) { int idx = tid * C + i; if (idx < n) s += counts[idx]; }
    part[tid] = s;
    __syncthreads();
    for (int off = 1; off < 1024; off <<= 1) {
        int v = (tid >= off) ? part[tid - off] : 0;
        __syncthreads();
        part[tid] += v;
        __syncthreads();
    }
    int base = (tid == 0) ? 0 : part[tid - 1];
    for (int i = 0; i < C; i++) {
        int idx = tid * C + i;
        if (idx < n) { row_ptr[idx] = base; cursor[idx] = base; base += counts[idx]; }
    }
    if (tid == 1023) row_ptr[n] = part[1023];
}

__global__ void scatter_kernel(const int* __restrict__ src, const int* __restrict__ dst,
                               int* __restrict__ cursor, int* __restrict__ src_sorted) {
    int t = blockIdx.x * blockDim.x + threadIdx.x;
    if (t >= N_EDGES) return;
    int pos = atomicAdd(&cursor[dst[t]], 1);
    src_sorted[pos] = src[t];
}

// ---------------------------------------------------------------------------
// Tiled fp32 GEMM: C[M,N] = A[M,K] @ B[K,N]; N%64==0, K%16==0
// ---------------------------------------------------------------------------
#define BM 64
#define BN 64
#define BK 16
__global__ __launch_bounds__(256) void gemm_rrr(const float* __restrict__ A,
                                                const float* __restrict__ B,
                                                float* __restrict__ C,
                                                int M, int N, int K) {
    __shared__ float As[BK][BM + 4];
    __shared__ float Bs[BK][BN + 4];
    int tid = threadIdx.x;
    int tx = tid & 15, ty = tid >> 4;
    int m0 = blockIdx.y * BM, n0 = blockIdx.x * BN;
    float acc[4][4] = {};
    int arow = tid >> 2;
    int akq  = (tid & 3) * 4;
    int brow = tid >> 4;
    int bcol = (tid & 15) * 4;
    for (int k0 = 0; k0 < K; k0 += BK) {
        int m = m0 + arow;
        float4 av = make_float4(0.f, 0.f, 0.f, 0.f);
        if (m < M) av = *(const float4*)(A + (size_t)m * K + k0 + akq);
        As[akq + 0][arow] = av.x; As[akq + 1][arow] = av.y;
        As[akq + 2][arow] = av.z; As[akq + 3][arow] = av.w;
        float4 bv = *(const float4*)(B + (size_t)(k0 + brow) * N + n0 + bcol);
        *(float4*)(&Bs[brow][bcol]) = bv;
        __syncthreads();
#pragma unroll
        for (int k = 0; k < BK; k++) {
            float4 a = *(const float4*)(&As[k][ty * 4]);
            float4 b = *(const float4*)(&Bs[k][tx * 4]);
            float av4[4] = {a.x, a.y, a.z, a.w};
            float bv4[4] = {b.x, b.y, b.z, b.w};
#pragma unroll
            for (int i = 0; i < 4; i++)
#pragma unroll
                for (int j = 0; j < 4; j++) acc[i][j] += av4[i] * bv4[j];
        }
        __syncthreads();
    }
#pragma unroll
    for (int i = 0; i < 4; i++) {
        int m = m0 + ty * 4 + i;
        if (m < M) {
#pragma unroll
            for (int j = 0; j < 4; j++)
                C[(size_t)m * N + n0 + tx * 4 + j] = acc[i][j];
        }
    }
}

// ---------------------------------------------------------------------------
// el/er: wave per (n,h); el[n*8+h] = sum_d feat[n,h*64+d]*al[h*64+d]
// ---------------------------------------------------------------------------
__global__ void elr_kernel(const float* __restrict__ feat, const float* __restrict__ al,
                           const float* __restrict__ ar, float* __restrict__ el,
                           float* __restrict__ er) {
    int lane = threadIdx.x & 63;
    int wid = (blockIdx.x * blockDim.x + threadIdx.x) >> 6;
    if (wid >= N_NODES * HEADS) return;
    int h = wid & 7;
    float f = feat[((size_t)(wid >> 3)) * HD + h * 64 + lane];
    float a = f * al[h * 64 + lane];
    float b = f * ar[h * 64 + lane];
    for (int off = 32; off; off >>= 1) { a += __shfl_down(a, off); b += __shfl_down(b, off); }
    if (lane == 0) { el[wid] = a; er[wid] = b; }
}

// ---------------------------------------------------------------------------
// edge softmax per (dst,h): thread per (n,h); alpha in CSR order [p*H+h]
// ---------------------------------------------------------------------------
__global__ void attn_kernel(const int* __restrict__ row_ptr, const int* __restrict__ src_sorted,
                            const float* __restrict__ el, const float* __restrict__ er,
                            float* __restrict__ alpha, int H) {
    int t = blockIdx.x * blockDim.x + threadIdx.x;
    if (t >= N_NODES * H) return;
    int n = t / H, h = t - n * H;
    int s0 = row_ptr[n], s1 = row_ptr[n + 1];
    float ern = er[t];
    float m = -1e30f;
    for (int p = s0; p < s1; p++) {
        float e = el[src_sorted[p] * H + h] + ern;
        e = e > 0.f ? e : 0.2f * e;
        m = fmaxf(m, e);
    }
    float sum = 0.f;
    for (int p = s0; p < s1; p++) {
        float e = el[src_sorted[p] * H + h] + ern;
        e = e > 0.f ? e : 0.2f * e;
        sum += expf(e - m);
    }
    float inv = 1.0f / fmaxf(sum, 1e-9f);
    for (int p = s0; p < s1; p++) {
        float e = el[src_sorted[p] * H + h] + ern;
        e = e > 0.f ? e : 0.2f * e;
        alpha[(size_t)p * H + h] = expf(e - m) * inv;
    }
}

// ---------------------------------------------------------------------------
// aggregation (H=8,D=64): wave per dst node, out = elu(sum alpha*feat[src] + b)
// ---------------------------------------------------------------------------
__global__ void agg_kernel(const int* __restrict__ row_ptr, const int* __restrict__ src_sorted,
                           const float* __restrict__ alpha, const float* __restrict__ feat,
                           const float* __restrict__ bias, float* __restrict__ out) {
    int lane = threadIdx.x & 63;
    int n = (blockIdx.x * blockDim.x + threadIdx.x) >> 6;
    if (n >= N_NODES) return;
    float acc[HEADS];
#pragma unroll
    for (int h = 0; h < HEADS; h++) acc[h] = 0.f;
    int s0 = row_ptr[n], s1 = row_ptr[n + 1];
    for (int p = s0; p < s1; p++) {
        int s = src_sorted[p];
        const float* fs = feat + (size_t)s * HD;
#pragma unroll
        for (int h = 0; h < HEADS; h++) {
            float a = alpha[(size_t)p * HEADS + h];
            acc[h] += a * fs[h * 64 + lane];
        }
    }
#pragma unroll
    for (int h = 0; h < HEADS; h++) {
        float x = acc[h] + bias[h * 64 + lane];
        out[(size_t)n * HD + h * 64 + lane] = x > 0.f ? x : expf(x) - 1.0f;
    }
}

// ---------------------------------------------------------------------------
// layer 2: small GEMM N=10, el/er (H=1,D=10), aggregation
// ---------------------------------------------------------------------------
__global__ void gemm_n10(const float* __restrict__ A, const float* __restrict__ B,
                         float* __restrict__ C, int K) {
    int t = blockIdx.x * blockDim.x + threadIdx.x;
    int m = t >> 4, c = t & 15;
    if (m >= N_NODES || c >= NCLS) return;
    const float* a = A + (size_t)m * K;
    float acc = 0.f;
    for (int k = 0; k < K; k++) acc += a[k] * B[k * NCLS + c];
    C[m * NCLS + c] = acc;
}

__global__ void elr2_kernel(const float* __restrict__ feat, const float* __restrict__ al,
                            const float* __restrict__ ar, float* __restrict__ el,
                            float* __restrict__ er) {
    int n = blockIdx.x * blockDim.x + threadIdx.x;
    if (n >= N_NODES) return;
    float a = 0.f, b = 0.f;
    for (int c = 0; c < NCLS; c++) {
        float f = feat[n * NCLS + c];
        a += f * al[c]; b += f * ar[c];
    }
    el[n] = a; er[n] = b;
}

__global__ void agg2_kernel(const int* __restrict__ row_ptr, const int* __restrict__ src_sorted,
                            const float* __restrict__ alpha, const float* __restrict__ feat,
                            const float* __restrict__ b2, float* __restrict__ out) {
    int t = blockIdx.x * blockDim.x + threadIdx.x;
    int n = t >> 4, c = t & 15;
    if (n >= N_NODES || c >= NCLS) return;
    float acc = b2[c];
    int s0 = row_ptr[n], s1 = row_ptr[n + 1];
    for (int p = s0; p < s1; p++)
        acc += alpha[p] * feat[src_sorted[p] * NCLS + c];
    out[n * NCLS + c] = acc;  // H=1: mean over heads is identity
}

// ---------------------------------------------------------------------------
extern "C" void kernel_launch(void* const* d_in, const int* in_sizes, int n_in,
                              void* d_out, int out_size, void* d_ws, size_t ws_size,
                              hipStream_t stream) {
    const float* feat0 = (const float*)d_in[0];
    const float* feat1 = (const float*)d_in[1];
    const float* fc0_w = (const float*)d_in[2];
    const float* fc0_b = (const float*)d_in[3];
    const float* fc1_w = (const float*)d_in[4];
    const float* fc1_b = (const float*)d_in[5];
    const float* W0    = (const float*)d_in[6];
    const float* al0   = (const float*)d_in[7];
    const float* ar0   = (const float*)d_in[8];
    const float* b0    = (const float*)d_in[9];
    const float* W1    = (const float*)d_in[10];
    const float* al1   = (const float*)d_in[11];
    const float* ar1   = (const float*)d_in[12];
    const float* b1    = (const float*)d_in[13];
    const float* W2    = (const float*)d_in[14];
    const float* al2   = (const float*)d_in[15];
    const float* ar2   = (const float*)d_in[16];
    const float* b2    = (const float*)d_in[17];
    const int* eidx    = (const int*)d_in[18];
    const int* src = eidx;
    const int* dst = eidx + N_EDGES;
    float* out = (float*)d_out;

    char* ws = (char*)d_ws;
    // workspace layout (bytes, all offsets 256-aligned)
    float* h0    = (float*)(ws + 0);               // 50000*64*4   = 12.8 MB (reused as feat2)
    float* bufA  = (float*)(ws + 12800000);        // 50000*512*4  = 102.4 MB
    float* bufB  = (float*)(ws + 115200000);       // 50000*512*4  = 102.4 MB
    float* el    = (float*)(ws + 217600000);       // 50000*8*4    = 1.6 MB
    float* er    = (float*)(ws + 219200000);       // 1.6 MB
    float* alpha = (float*)(ws + 220800000);       // 500000*8*4   = 16 MB
    int*   cnt   = (int*)  (ws + 236800000);       // 50000*4
    int*   rp    = (int*)  (ws + 237000192);       // 50001*4
    int*   cur   = (int*)  (ws + 237200384);       // 50000*4
    int*   srcs  = (int*)  (ws + 237400576);       // 500000*4
    float* feat2 = h0;                             // 50000*10*4 = 2 MB, h0 dead by then

    // --- fc projection ---
    fc_kernel<<<(N_NODES * 64 + 255) / 256, 256, 0, stream>>>(feat0, feat1, fc0_w, fc0_b,
                                                              fc1_w, fc1_b, h0);
    // --- CSR build ---
    hipMemsetAsync(cnt, 0, N_NODES * sizeof(int), stream);
    count_kernel<<<(N_EDGES + 255) / 256, 256, 0, stream>>>(dst, cnt);
    scan_kernel<<<1, 1024, 0, stream>>>(cnt, rp, cur);
    scatter_kernel<<<(N_EDGES + 255) / 256, 256, 0, stream>>>(src, dst, cur, srcs);

    dim3 ggrid(HD / BN, (N_NODES + BM - 1) / BM);

    // --- layer 0 ---
    gemm_rrr<<<ggrid, 256, 0, stream>>>(h0, W0, bufA, N_NODES, HD, 64);
    elr_kernel<<<(N_NODES * HEADS + 3) / 4, 256, 0, stream>>>(bufA, al0, ar0, el, er);
    attn_kernel<<<(N_NODES * HEADS + 255) / 256, 256, 0, stream>>>(rp, srcs, el, er, alpha, HEADS);
    agg_kernel<<<(N_NODES + 3) / 4, 256, 0, stream>>>(rp, srcs, alpha, bufA, b0, bufB);

    // --- layer 1 ---
    gemm_rrr<<<ggrid, 256, 0, stream>>>(bufB, W1, bufA, N_NODES, HD, HD);
    elr_kernel<<<(N_NODES * HEADS + 3) / 4, 256, 0, stream>>>(bufA, al1, ar1, el, er);
    attn_kernel<<<(N_NODES * HEADS + 255) / 256, 256, 0, stream>>>(rp, srcs, el, er, alpha, HEADS);
    agg_kernel<<<(N_NODES + 3) / 4, 256, 0, stream>>>(rp, srcs, alpha, bufA, b1, bufB);

    // --- layer 2 ---
    gemm_n10<<<(N_NODES * 16 + 255) / 256, 256, 0, stream>>>(bufB, W2, feat2, HD);
    elr2_kernel<<<(N_NODES + 255) / 256, 256, 0, stream>>>(feat2, al2, ar2, el, er);
    attn_kernel<<<(N_NODES + 255) / 256, 256, 0, stream>>>(rp, srcs, el, er, alpha, 1);
    agg2_kernel<<<(N_NODES * 16 + 255) / 256, 256, 0, stream>>>(rp, srcs, alpha, feat2, b2, out);
}

// Round 2
// 1223.142 us; speedup vs baseline: 1.3571x; 1.3571x over previous
//
#include <hip/hip_runtime.h>
#include <hip/hip_bf16.h>

#define N_NODES 50000
#define N_EDGES 500000
#define HEADS 8
#define HID 64
#define HD 512   // HEADS*HID
#define NCLS 10
#define M_PAD 50048  // 391*128, GEMM M padded to tile

typedef __bf16 bf16x8 __attribute__((ext_vector_type(8)));
typedef float  f32x4  __attribute__((ext_vector_type(4)));

#define GLD_LDS16(g, l) __builtin_amdgcn_global_load_lds( \
    (__attribute__((address_space(1))) void*)(g),         \
    (__attribute__((address_space(3))) void*)(l), 16, 0, 0)

// ---------------------------------------------------------------------------
// fc projection: h[n,j] = feat_type(n) @ fcW + fcb  (j<64), output bf16
// ---------------------------------------------------------------------------
__global__ void fc_kernel(const float* __restrict__ f0, const float* __restrict__ f1,
                          const float* __restrict__ w0, const float* __restrict__ b0,
                          const float* __restrict__ w1, const float* __restrict__ b1,
                          __hip_bfloat16* __restrict__ h) {
    int t = blockIdx.x * blockDim.x + threadIdx.x;
    if (t >= N_NODES * 64) return;
    int n = t >> 6, j = t & 63;
    const float* f; const float* w; const float* b; int K;
    if (n < 30000) { f = f0 + (size_t)n * 256; w = w0; b = b0; K = 256; }
    else           { f = f1 + (size_t)(n - 30000) * 128; w = w1; b = b1; K = 128; }
    float acc = b[j];
    for (int k = 0; k < K; k++) acc += f[k] * w[k * 64 + j];
    h[t] = __float2bfloat16(acc);
}

// ---------------------------------------------------------------------------
// CSR build: count -> parallel scan (3 kernels) -> scatter
// ---------------------------------------------------------------------------
#define NBLK_SCAN 196  // ceil(50000/256)

__global__ void count_kernel(const int* __restrict__ dst, int* __restrict__ cnt) {
    int t = blockIdx.x * blockDim.x + threadIdx.x;
    if (t < N_EDGES) atomicAdd(&cnt[dst[t]], 1);
}

__global__ void scan_part(const int* __restrict__ cnt, int* __restrict__ part) {
    __shared__ int s[256];
    int i = blockIdx.x * 256 + threadIdx.x;
    s[threadIdx.x] = (i < N_NODES) ? cnt[i] : 0;
    __syncthreads();
    for (int off = 128; off; off >>= 1) {
        if (threadIdx.x < off) s[threadIdx.x] += s[threadIdx.x + off];
        __syncthreads();
    }
    if (threadIdx.x == 0) part[blockIdx.x] = s[0];
}

__global__ void scan_offs(int* __restrict__ part) {
    if (threadIdx.x == 0 && blockIdx.x == 0) {
        int s = 0;
        for (int i = 0; i < NBLK_SCAN; i++) { int v = part[i]; part[i] = s; s += v; }
    }
}

__global__ void scan_apply(const int* __restrict__ cnt, const int* __restrict__ part,
                           int* __restrict__ rp, int* __restrict__ cur) {
    __shared__ int s[256];
    int tid = threadIdx.x;
    int i = blockIdx.x * 256 + tid;
    int v = (i < N_NODES) ? cnt[i] : 0;
    s[tid] = v;
    __syncthreads();
    for (int off = 1; off < 256; off <<= 1) {
        int x = (tid >= off) ? s[tid - off] : 0;
        __syncthreads();
        s[tid] += x;
        __syncthreads();
    }
    if (i < N_NODES) {
        int excl = s[tid] - v + part[blockIdx.x];
        rp[i] = excl; cur[i] = excl;
    }
    if (i == 0) rp[N_NODES] = N_EDGES;
}

__global__ void scatter_kernel(const int* __restrict__ src, const int* __restrict__ dst,
                               int* __restrict__ cursor, int* __restrict__ src_sorted) {
    int t = blockIdx.x * blockDim.x + threadIdx.x;
    if (t >= N_EDGES) return;
    int pos = atomicAdd(&cursor[dst[t]], 1);
    src_sorted[pos] = src[t];
}

// ---------------------------------------------------------------------------
// weight transpose+cast: Wt[n][k] = bf16(W[k][n])
// ---------------------------------------------------------------------------
__global__ void wtrans(const float* __restrict__ W, __hip_bfloat16* __restrict__ Wt,
                       int Kdim, int Ndim) {
    int t = blockIdx.x * blockDim.x + threadIdx.x;
    if (t >= Kdim * Ndim) return;
    int n = t / Kdim, k = t - n * Kdim;
    Wt[t] = __float2bfloat16(W[k * Ndim + n]);
}

// ---------------------------------------------------------------------------
// bf16 MFMA GEMM: C[M,N]f32 = A[M_pad,K]bf16 @ Bt[N,K]bf16^T
// 128x128 tile, BK=32, 4 waves, 4x4 16x16x32 MFMAs per wave.
// LDS kgroup XOR-swizzle (memory-side) to cut ds_read_b128 bank conflicts.
// ---------------------------------------------------------------------------
__global__ __launch_bounds__(256) void gemm_mfma(const ushort* __restrict__ A,
                                                 const ushort* __restrict__ Bt,
                                                 float* __restrict__ C,
                                                 int M, int N, int K) {
    __shared__ ushort Asl[128 * 32];
    __shared__ ushort Bsl[128 * 32];
    int t = threadIdx.x;
    int m0 = blockIdx.y * 128, n0 = blockIdx.x * 128;
    int lane = t & 63;
    int w = t >> 6;
    int wm = (w & 1) * 64, wn = (w >> 1) * 64;
    int l15 = lane & 15, quad = lane >> 4;
    f32x4 acc[4][4];
#pragma unroll
    for (int i = 0; i < 4; i++)
#pragma unroll
        for (int j = 0; j < 4; j++) acc[i][j] = (f32x4){0.f, 0.f, 0.f, 0.f};

    // staging byte-flat indices (each thread moves 2x16B per tile)
    int fb0 = t * 16;
    int fb1 = fb0 + 4096;
    int row0 = fb0 >> 6, kg0 = ((fb0 >> 4) & 3) ^ (row0 & 3);
    int row1 = fb1 >> 6, kg1 = ((fb1 >> 4) & 3) ^ (row1 & 3);

    for (int k0 = 0; k0 < K; k0 += 32) {
        GLD_LDS16(A + (size_t)(m0 + row0) * K + k0 + kg0 * 8, (char*)Asl + fb0);
        GLD_LDS16(A + (size_t)(m0 + row1) * K + k0 + kg1 * 8, (char*)Asl + fb1);
        GLD_LDS16(Bt + (size_t)(n0 + row0) * K + k0 + kg0 * 8, (char*)Bsl + fb0);
        GLD_LDS16(Bt + (size_t)(n0 + row1) * K + k0 + kg1 * 8, (char*)Bsl + fb1);
        __syncthreads();
        bf16x8 af[4], bfr[4];
#pragma unroll
        for (int i = 0; i < 4; i++) {
            int r = wm + i * 16 + l15;
            int kg = quad ^ (r & 3);
            af[i] = *(const bf16x8*)(Asl + r * 32 + kg * 8);
        }
#pragma unroll
        for (int j = 0; j < 4; j++) {
            int r = wn + j * 16 + l15;
            int kg = quad ^ (r & 3);
            bfr[j] = *(const bf16x8*)(Bsl + r * 32 + kg * 8);
        }
#pragma unroll
        for (int i = 0; i < 4; i++)
#pragma unroll
            for (int j = 0; j < 4; j++)
                acc[i][j] = __builtin_amdgcn_mfma_f32_16x16x32_bf16(af[i], bfr[j], acc[i][j], 0, 0, 0);
        __syncthreads();
    }
    // C/D layout: col = lane&15, row = quad*4 + reg  [m89/m91 verified]
#pragma unroll
    for (int i = 0; i < 4; i++) {
        int rbase = m0 + wm + i * 16 + quad * 4;
#pragma unroll
        for (int j = 0; j < 4; j++) {
            int col = n0 + wn + j * 16 + l15;
#pragma unroll
            for (int r = 0; r < 4; r++) {
                int row = rbase + r;
                if (row < M) C[(size_t)row * N + col] = acc[i][j][r];
            }
        }
    }
}

// ---------------------------------------------------------------------------
// el/er: wave per (n,h)
// ---------------------------------------------------------------------------
__global__ void elr_kernel(const float* __restrict__ feat, const float* __restrict__ al,
                           const float* __restrict__ ar, float* __restrict__ el,
                           float* __restrict__ er) {
    int lane = threadIdx.x & 63;
    int wid = (blockIdx.x * blockDim.x + threadIdx.x) >> 6;
    if (wid >= N_NODES * HEADS) return;
    int h = wid & 7;
    float f = feat[((size_t)(wid >> 3)) * HD + h * 64 + lane];
    float a = f * al[h * 64 + lane];
    float b = f * ar[h * 64 + lane];
    for (int off = 32; off; off >>= 1) { a += __shfl_down(a, off); b += __shfl_down(b, off); }
    if (lane == 0) { el[wid] = a; er[wid] = b; }
}

// ---------------------------------------------------------------------------
// edge softmax per (dst,h)
// ---------------------------------------------------------------------------
__global__ void attn_kernel(const int* __restrict__ row_ptr, const int* __restrict__ src_sorted,
                            const float* __restrict__ el, const float* __restrict__ er,
                            float* __restrict__ alpha, int H) {
    int t = blockIdx.x * blockDim.x + threadIdx.x;
    if (t >= N_NODES * H) return;
    int n = t / H, h = t - n * H;
    int s0 = row_ptr[n], s1 = row_ptr[n + 1];
    float ern = er[t];
    float m = -1e30f;
    for (int p = s0; p < s1; p++) {
        float e = el[src_sorted[p] * H + h] + ern;
        e = e > 0.f ? e : 0.2f * e;
        m = fmaxf(m, e);
    }
    float sum = 0.f;
    for (int p = s0; p < s1; p++) {
        float e = el[src_sorted[p] * H + h] + ern;
        e = e > 0.f ? e : 0.2f * e;
        sum += expf(e - m);
    }
    float inv = 1.0f / fmaxf(sum, 1e-9f);
    for (int p = s0; p < s1; p++) {
        float e = el[src_sorted[p] * H + h] + ern;
        e = e > 0.f ? e : 0.2f * e;
        alpha[(size_t)p * H + h] = expf(e - m) * inv;
    }
}

// ---------------------------------------------------------------------------
// aggregation (H=8,D=64): wave per dst node; out = elu(sum alpha*feat[src]+b)
// ---------------------------------------------------------------------------
__device__ __forceinline__ void store_val(float* p, float v) { *p = v; }
__device__ __forceinline__ void store_val(__hip_bfloat16* p, float v) { *p = __float2bfloat16(v); }

template <typename OUT>
__global__ void agg_kernel(const int* __restrict__ row_ptr, const int* __restrict__ src_sorted,
                           const float* __restrict__ alpha, const float* __restrict__ feat,
                           const float* __restrict__ bias, OUT* __restrict__ out) {
    int lane = threadIdx.x & 63;
    int n = (blockIdx.x * blockDim.x + threadIdx.x) >> 6;
    if (n >= N_NODES) return;
    float acc[HEADS];
#pragma unroll
    for (int h = 0; h < HEADS; h++) acc[h] = 0.f;
    int s0 = row_ptr[n], s1 = row_ptr[n + 1];
    for (int p = s0; p < s1; p++) {
        int s = src_sorted[p];
        const float* fs = feat + (size_t)s * HD;
#pragma unroll
        for (int h = 0; h < HEADS; h++) {
            float a = alpha[(size_t)p * HEADS + h];
            acc[h] += a * fs[h * 64 + lane];
        }
    }
#pragma unroll
    for (int h = 0; h < HEADS; h++) {
        float x = acc[h] + bias[h * 64 + lane];
        float y = x > 0.f ? x : expf(x) - 1.0f;
        store_val(out + (size_t)n * HD + h * 64 + lane, y);
    }
}

// ---------------------------------------------------------------------------
// layer 2 (fp32 path): small GEMM N=10, el/er (H=1,D=10), aggregation
// ---------------------------------------------------------------------------
__global__ void gemm_n10(const float* __restrict__ A, const float* __restrict__ B,
                         float* __restrict__ C, int K) {
    int t = blockIdx.x * blockDim.x + threadIdx.x;
    int m = t >> 4, c = t & 15;
    if (m >= N_NODES || c >= NCLS) return;
    const float* a = A + (size_t)m * K;
    float acc = 0.f;
    for (int k = 0; k < K; k++) acc += a[k] * B[k * NCLS + c];
    C[m * NCLS + c] = acc;
}

__global__ void elr2_kernel(const float* __restrict__ feat, const float* __restrict__ al,
                            const float* __restrict__ ar, float* __restrict__ el,
                            float* __restrict__ er) {
    int n = blockIdx.x * blockDim.x + threadIdx.x;
    if (n >= N_NODES) return;
    float a = 0.f, b = 0.f;
    for (int c = 0; c < NCLS; c++) {
        float f = feat[n * NCLS + c];
        a += f * al[c]; b += f * ar[c];
    }
    el[n] = a; er[n] = b;
}

__global__ void agg2_kernel(const int* __restrict__ row_ptr, const int* __restrict__ src_sorted,
                            const float* __restrict__ alpha, const float* __restrict__ feat,
                            const float* __restrict__ b2, float* __restrict__ out) {
    int t = blockIdx.x * blockDim.x + threadIdx.x;
    int n = t >> 4, c = t & 15;
    if (n >= N_NODES || c >= NCLS) return;
    float acc = b2[c];
    int s0 = row_ptr[n], s1 = row_ptr[n + 1];
    for (int p = s0; p < s1; p++)
        acc += alpha[p] * feat[src_sorted[p] * NCLS + c];
    out[n * NCLS + c] = acc;  // H=1: mean over heads is identity
}

// ---------------------------------------------------------------------------
extern "C" void kernel_launch(void* const* d_in, const int* in_sizes, int n_in,
                              void* d_out, int out_size, void* d_ws, size_t ws_size,
                              hipStream_t stream) {
    const float* feat0 = (const float*)d_in[0];
    const float* feat1 = (const float*)d_in[1];
    const float* fc0_w = (const float*)d_in[2];
    const float* fc0_b = (const float*)d_in[3];
    const float* fc1_w = (const float*)d_in[4];
    const float* fc1_b = (const float*)d_in[5];
    const float* W0    = (const float*)d_in[6];
    const float* al0   = (const float*)d_in[7];
    const float* ar0   = (const float*)d_in[8];
    const float* b0    = (const float*)d_in[9];
    const float* W1    = (const float*)d_in[10];
    const float* al1   = (const float*)d_in[11];
    const float* ar1   = (const float*)d_in[12];
    const float* b1    = (const float*)d_in[13];
    const float* W2    = (const float*)d_in[14];
    const float* al2   = (const float*)d_in[15];
    const float* ar2   = (const float*)d_in[16];
    const float* b2    = (const float*)d_in[17];
    const int* eidx    = (const int*)d_in[18];
    const int* src = eidx;
    const int* dst = eidx + N_EDGES;
    float* out = (float*)d_out;

    char* ws = (char*)d_ws;
    // workspace layout (bytes; aggbf/aggf32 share a region — disjoint lifetimes)
    float*          featA  = (float*)         (ws + 0);           // 50000*512*4 = 102,400,000
    __hip_bfloat16* aggbf  = (__hip_bfloat16*)(ws + 102400000);   // 50048*512*2 = 51,249,152
    float*          aggf32 = (float*)         (ws + 102400000);   // 50000*512*4 (after aggbf dead)
    __hip_bfloat16* h0bf   = (__hip_bfloat16*)(ws + 204800000);   // 50048*64*2 = 6,406,144
    float*          feat2  = (float*)         (ws + 211206400);   // 50000*10*4 = 2,000,000
    float*          el     = (float*)         (ws + 213206528);   // 1,600,000
    float*          er     = (float*)         (ws + 214806784);   // 1,600,000
    float*          alpha  = (float*)         (ws + 216407040);   // 16,000,000
    int*            cnt    = (int*)           (ws + 232407296);   // 200,000
    int*            rp     = (int*)           (ws + 232607488);   // 200,004
    int*            cur    = (int*)           (ws + 232807680);   // 200,000
    int*            srcs   = (int*)           (ws + 233007872);   // 2,000,000
    int*            part   = (int*)           (ws + 235008000);   // 1,024
    __hip_bfloat16* W0t    = (__hip_bfloat16*)(ws + 235009024);   // 512*64*2 = 65,536
    __hip_bfloat16* W1t    = (__hip_bfloat16*)(ws + 235074816);   // 512*512*2 = 524,288

    // --- fc projection (bf16 out) ---
    fc_kernel<<<(N_NODES * 64 + 255) / 256, 256, 0, stream>>>(feat0, feat1, fc0_w, fc0_b,
                                                              fc1_w, fc1_b, h0bf);
    // --- weight transpose+cast ---
    wtrans<<<(512 * 64 + 255) / 256, 256, 0, stream>>>(W0, W0t, 64, 512);
    wtrans<<<(512 * 512 + 255) / 256, 256, 0, stream>>>(W1, W1t, 512, 512);

    // --- CSR build ---
    hipMemsetAsync(cnt, 0, N_NODES * sizeof(int), stream);
    count_kernel<<<(N_EDGES + 255) / 256, 256, 0, stream>>>(dst, cnt);
    scan_part<<<NBLK_SCAN, 256, 0, stream>>>(cnt, part);
    scan_offs<<<1, 64, 0, stream>>>(part);
    scan_apply<<<NBLK_SCAN, 256, 0, stream>>>(cnt, part, rp, cur);
    scatter_kernel<<<(N_EDGES + 255) / 256, 256, 0, stream>>>(src, dst, cur, srcs);

    dim3 ggrid(HD / 128, M_PAD / 128);  // (4, 391)

    // --- layer 0 ---
    gemm_mfma<<<ggrid, 256, 0, stream>>>((const ushort*)h0bf, (const ushort*)W0t, featA,
                                         N_NODES, HD, 64);
    elr_kernel<<<(N_NODES * HEADS + 3) / 4, 256, 0, stream>>>(featA, al0, ar0, el, er);
    attn_kernel<<<(N_NODES * HEADS + 255) / 256, 256, 0, stream>>>(rp, srcs, el, er, alpha, HEADS);
    agg_kernel<<<(N_NODES + 3) / 4, 256, 0, stream>>>(rp, srcs, alpha, featA, b0, aggbf);

    // --- layer 1 ---
    gemm_mfma<<<ggrid, 256, 0, stream>>>((const ushort*)aggbf, (const ushort*)W1t, featA,
                                         N_NODES, HD, HD);
    elr_kernel<<<(N_NODES * HEADS + 3) / 4, 256, 0, stream>>>(featA, al1, ar1, el, er);
    attn_kernel<<<(N_NODES * HEADS + 255) / 256, 256, 0, stream>>>(rp, srcs, el, er, alpha, HEADS);
    agg_kernel<<<(N_NODES + 3) / 4, 256, 0, stream>>>(rp, srcs, alpha, featA, b1, aggf32);

    // --- layer 2 (fp32) ---
    gemm_n10<<<(N_NODES * 16 + 255) / 256, 256, 0, stream>>>(aggf32, W2, feat2, HD);
    elr2_kernel<<<(N_NODES + 255) / 256, 256, 0, stream>>>(feat2, al2, ar2, el, er);
    attn_kernel<<<(N_NODES + 255) / 256, 256, 0, stream>>>(rp, srcs, el, er, alpha, 1);
    agg2_kernel<<<(N_NODES * 16 + 255) / 256, 256, 0, stream>>>(rp, srcs, alpha, feat2, b2, out);
}

// Round 3
// 622.355 us; speedup vs baseline: 2.6672x; 1.9653x over previous
//
#include <hip/hip_runtime.h>
#include <hip/hip_bf16.h>

#define N_NODES 50000
#define N_EDGES 500000
#define HEADS 8
#define HID 64
#define HD 512   // HEADS*HID
#define NCLS 10
#define M_PAD 50048  // 391*128, GEMM M padded to tile

typedef __bf16 bf16x8 __attribute__((ext_vector_type(8)));
typedef float  f32x4  __attribute__((ext_vector_type(4)));

#define GLD_LDS16(g, l) __builtin_amdgcn_global_load_lds( \
    (__attribute__((address_space(1))) void*)(g),         \
    (__attribute__((address_space(3))) void*)(l), 16, 0, 0)

// ---------------------------------------------------------------------------
// fc projection as tiled fp32 GEMM (64x64 tile, BK=16), epilogue: +bias, bf16
// C rows written at row_off into h0bf [M_PAD x 64]
// ---------------------------------------------------------------------------
__global__ __launch_bounds__(256) void fc_gemm(const float* __restrict__ A,
                                               const float* __restrict__ B,
                                               const float* __restrict__ bias,
                                               __hip_bfloat16* __restrict__ Cb,
                                               int M, int K, int row_off) {
    __shared__ float As[16][64 + 4];
    __shared__ float Bs[16][64 + 4];
    int tid = threadIdx.x;
    int tx = tid & 15, ty = tid >> 4;
    int m0 = blockIdx.y * 64;
    float acc[4][4] = {};
    int arow = tid >> 2;
    int akq  = (tid & 3) * 4;
    int brow = tid >> 4;
    int bcol = (tid & 15) * 4;
    for (int k0 = 0; k0 < K; k0 += 16) {
        int m = m0 + arow;
        float4 av = make_float4(0.f, 0.f, 0.f, 0.f);
        if (m < M) av = *(const float4*)(A + (size_t)m * K + k0 + akq);
        As[akq + 0][arow] = av.x; As[akq + 1][arow] = av.y;
        As[akq + 2][arow] = av.z; As[akq + 3][arow] = av.w;
        float4 bv = *(const float4*)(B + (size_t)(k0 + brow) * 64 + bcol);
        *(float4*)(&Bs[brow][bcol]) = bv;
        __syncthreads();
#pragma unroll
        for (int k = 0; k < 16; k++) {
            float4 a = *(const float4*)(&As[k][ty * 4]);
            float4 b = *(const float4*)(&Bs[k][tx * 4]);
            float av4[4] = {a.x, a.y, a.z, a.w};
            float bv4[4] = {b.x, b.y, b.z, b.w};
#pragma unroll
            for (int i = 0; i < 4; i++)
#pragma unroll
                for (int j = 0; j < 4; j++) acc[i][j] += av4[i] * bv4[j];
        }
        __syncthreads();
    }
#pragma unroll
    for (int i = 0; i < 4; i++) {
        int m = m0 + ty * 4 + i;
        if (m < M) {
#pragma unroll
            for (int j = 0; j < 4; j++) {
                int col = tx * 4 + j;
                Cb[(size_t)(row_off + m) * 64 + col] = __float2bfloat16(acc[i][j] + bias[col]);
            }
        }
    }
}

// ---------------------------------------------------------------------------
// CSR build: count -> parallel scan (3 kernels) -> scatter
// ---------------------------------------------------------------------------
#define NBLK_SCAN 196  // ceil(50000/256)

__global__ void count_kernel(const int* __restrict__ dst, int* __restrict__ cnt) {
    int t = blockIdx.x * blockDim.x + threadIdx.x;
    if (t < N_EDGES) atomicAdd(&cnt[dst[t]], 1);
}

__global__ void scan_part(const int* __restrict__ cnt, int* __restrict__ part) {
    __shared__ int s[256];
    int i = blockIdx.x * 256 + threadIdx.x;
    s[threadIdx.x] = (i < N_NODES) ? cnt[i] : 0;
    __syncthreads();
    for (int off = 128; off; off >>= 1) {
        if (threadIdx.x < off) s[threadIdx.x] += s[threadIdx.x + off];
        __syncthreads();
    }
    if (threadIdx.x == 0) part[blockIdx.x] = s[0];
}

__global__ void scan_offs(int* __restrict__ part) {
    if (threadIdx.x == 0 && blockIdx.x == 0) {
        int s = 0;
        for (int i = 0; i < NBLK_SCAN; i++) { int v = part[i]; part[i] = s; s += v; }
    }
}

__global__ void scan_apply(const int* __restrict__ cnt, const int* __restrict__ part,
                           int* __restrict__ rp, int* __restrict__ cur) {
    __shared__ int s[256];
    int tid = threadIdx.x;
    int i = blockIdx.x * 256 + tid;
    int v = (i < N_NODES) ? cnt[i] : 0;
    s[tid] = v;
    __syncthreads();
    for (int off = 1; off < 256; off <<= 1) {
        int x = (tid >= off) ? s[tid - off] : 0;
        __syncthreads();
        s[tid] += x;
        __syncthreads();
    }
    if (i < N_NODES) {
        int excl = s[tid] - v + part[blockIdx.x];
        rp[i] = excl; cur[i] = excl;
    }
    if (i == 0) rp[N_NODES] = N_EDGES;
}

__global__ void scatter_kernel(const int* __restrict__ src, const int* __restrict__ dst,
                               int* __restrict__ cursor, int* __restrict__ src_sorted) {
    int t = blockIdx.x * blockDim.x + threadIdx.x;
    if (t >= N_EDGES) return;
    int pos = atomicAdd(&cursor[dst[t]], 1);
    src_sorted[pos] = src[t];
}

// ---------------------------------------------------------------------------
// weight transpose+cast: Wt[n][k] = bf16(W[k][n])
// ---------------------------------------------------------------------------
__global__ void wtrans(const float* __restrict__ W, __hip_bfloat16* __restrict__ Wt,
                       int Kdim, int Ndim) {
    int t = blockIdx.x * blockDim.x + threadIdx.x;
    if (t >= Kdim * Ndim) return;
    int n = t / Kdim, k = t - n * Kdim;
    Wt[t] = __float2bfloat16(W[k * Ndim + n]);
}

// ---------------------------------------------------------------------------
// bf16 MFMA GEMM: Cb[M,N]bf16 = A[M_pad,K]bf16 @ Bt[N,K]bf16^T
// 128x128 tile, BK=32, 4 waves, 4x4 16x16x32 MFMAs per wave.
// Fused epilogue: el[n,h] = sum_d C[n,h*64+d]*al[h*64+d] (each wave = 1 head).
// ---------------------------------------------------------------------------
__global__ __launch_bounds__(256) void gemm_mfma(const ushort* __restrict__ A,
                                                 const ushort* __restrict__ Bt,
                                                 __hip_bfloat16* __restrict__ Cb,
                                                 const float* __restrict__ al,
                                                 const float* __restrict__ ar,
                                                 float* __restrict__ el,
                                                 float* __restrict__ er,
                                                 int M, int N, int K) {
    __shared__ ushort Asl[128 * 32];
    __shared__ ushort Bsl[128 * 32];
    int t = threadIdx.x;
    int m0 = blockIdx.y * 128, n0 = blockIdx.x * 128;
    int lane = t & 63;
    int w = t >> 6;
    int wm = (w & 1) * 64, wn = (w >> 1) * 64;
    int l15 = lane & 15, quad = lane >> 4;
    f32x4 acc[4][4];
#pragma unroll
    for (int i = 0; i < 4; i++)
#pragma unroll
        for (int j = 0; j < 4; j++) acc[i][j] = (f32x4){0.f, 0.f, 0.f, 0.f};

    int fb0 = t * 16;
    int fb1 = fb0 + 4096;
    int row0 = fb0 >> 6, kg0 = ((fb0 >> 4) & 3) ^ (row0 & 3);
    int row1 = fb1 >> 6, kg1 = ((fb1 >> 4) & 3) ^ (row1 & 3);

    for (int k0 = 0; k0 < K; k0 += 32) {
        GLD_LDS16(A + (size_t)(m0 + row0) * K + k0 + kg0 * 8, (char*)Asl + fb0);
        GLD_LDS16(A + (size_t)(m0 + row1) * K + k0 + kg1 * 8, (char*)Asl + fb1);
        GLD_LDS16(Bt + (size_t)(n0 + row0) * K + k0 + kg0 * 8, (char*)Bsl + fb0);
        GLD_LDS16(Bt + (size_t)(n0 + row1) * K + k0 + kg1 * 8, (char*)Bsl + fb1);
        __syncthreads();
        bf16x8 af[4], bfr[4];
#pragma unroll
        for (int i = 0; i < 4; i++) {
            int r = wm + i * 16 + l15;
            int kg = quad ^ (r & 3);
            af[i] = *(const bf16x8*)(Asl + r * 32 + kg * 8);
        }
#pragma unroll
        for (int j = 0; j < 4; j++) {
            int r = wn + j * 16 + l15;
            int kg = quad ^ (r & 3);
            bfr[j] = *(const bf16x8*)(Bsl + r * 32 + kg * 8);
        }
#pragma unroll
        for (int i = 0; i < 4; i++)
#pragma unroll
            for (int j = 0; j < 4; j++)
                acc[i][j] = __builtin_amdgcn_mfma_f32_16x16x32_bf16(af[i], bfr[j], acc[i][j], 0, 0, 0);
        __syncthreads();
    }
    // C/D layout: col = l15, row = quad*4 + reg  [m89/m91 verified]
#pragma unroll
    for (int i = 0; i < 4; i++) {
        int rbase = m0 + wm + i * 16 + quad * 4;
#pragma unroll
        for (int j = 0; j < 4; j++) {
            int col = n0 + wn + j * 16 + l15;
#pragma unroll
            for (int r = 0; r < 4; r++) {
                int row = rbase + r;
                if (row < M) Cb[(size_t)row * N + col] = __float2bfloat16(acc[i][j][r]);
            }
        }
    }
    // fused el/er: this wave's 64 cols = head h, exactly
    int h = (n0 + wn) >> 6;
    float alv[4], arv[4];
#pragma unroll
    for (int j = 0; j < 4; j++) {
        alv[j] = al[h * 64 + j * 16 + l15];
        arv[j] = ar[h * 64 + j * 16 + l15];
    }
#pragma unroll
    for (int i = 0; i < 4; i++) {
#pragma unroll
        for (int r = 0; r < 4; r++) {
            float sl = 0.f, sr = 0.f;
#pragma unroll
            for (int j = 0; j < 4; j++) {
                float v = acc[i][j][r];
                sl += v * alv[j]; sr += v * arv[j];
            }
#pragma unroll
            for (int mk = 1; mk < 16; mk <<= 1) {
                sl += __shfl_xor(sl, mk);
                sr += __shfl_xor(sr, mk);
            }
            int row = m0 + wm + i * 16 + quad * 4 + r;
            if (l15 == 0 && row < M) {
                el[row * HEADS + h] = sl;
                er[row * HEADS + h] = sr;
            }
        }
    }
}

// ---------------------------------------------------------------------------
// edge softmax per (dst,h): pass1 gather e -> alpha; pass2/3 sequential
// ---------------------------------------------------------------------------
__global__ void attn_kernel(const int* __restrict__ row_ptr, const int* __restrict__ src_sorted,
                            const float* __restrict__ el, const float* __restrict__ er,
                            float* __restrict__ alpha, int H) {
    int t = blockIdx.x * blockDim.x + threadIdx.x;
    if (t >= N_NODES * H) return;
    int n = t / H, h = t - n * H;
    int s0 = row_ptr[n], s1 = row_ptr[n + 1];
    float ern = er[t];
    float m = -1e30f;
    for (int p = s0; p < s1; p++) {
        float e = el[src_sorted[p] * H + h] + ern;
        e = e > 0.f ? e : 0.2f * e;
        alpha[(size_t)p * H + h] = e;
        m = fmaxf(m, e);
    }
    float sum = 0.f;
    for (int p = s0; p < s1; p++) {
        float ee = expf(alpha[(size_t)p * H + h] - m);
        alpha[(size_t)p * H + h] = ee;
        sum += ee;
    }
    float inv = 1.0f / fmaxf(sum, 1e-9f);
    for (int p = s0; p < s1; p++)
        alpha[(size_t)p * H + h] *= inv;
}

// ---------------------------------------------------------------------------
// aggregation (H=8,D=64): wave per dst node; out = elu(sum alpha*feat[src]+b)
// feat is bf16 [M_PAD x 512]
// ---------------------------------------------------------------------------
__device__ __forceinline__ void store_val(float* p, float v) { *p = v; }
__device__ __forceinline__ void store_val(__hip_bfloat16* p, float v) { *p = __float2bfloat16(v); }

template <typename OUT>
__global__ void agg_kernel(const int* __restrict__ row_ptr, const int* __restrict__ src_sorted,
                           const float* __restrict__ alpha, const __hip_bfloat16* __restrict__ feat,
                           const float* __restrict__ bias, OUT* __restrict__ out) {
    int lane = threadIdx.x & 63;
    int n = (blockIdx.x * blockDim.x + threadIdx.x) >> 6;
    if (n >= N_NODES) return;
    float acc[HEADS];
#pragma unroll
    for (int h = 0; h < HEADS; h++) acc[h] = 0.f;
    int s0 = row_ptr[n], s1 = row_ptr[n + 1];
    for (int p = s0; p < s1; p++) {
        int s = src_sorted[p];
        const __hip_bfloat16* fs = feat + (size_t)s * HD;
#pragma unroll
        for (int h = 0; h < HEADS; h++) {
            float a = alpha[(size_t)p * HEADS + h];
            acc[h] += a * __bfloat162float(fs[h * 64 + lane]);
        }
    }
#pragma unroll
    for (int h = 0; h < HEADS; h++) {
        float x = acc[h] + bias[h * 64 + lane];
        float y = x > 0.f ? x : expf(x) - 1.0f;
        store_val(out + (size_t)n * HD + h * 64 + lane, y);
    }
}

// ---------------------------------------------------------------------------
// layer 2: wave-per-row GEMM (N=10), B in LDS stride-11; elr2; agg2
// ---------------------------------------------------------------------------
__global__ __launch_bounds__(256) void gemm_n10v2(const float* __restrict__ A,
                                                  const float* __restrict__ B,
                                                  float* __restrict__ C) {
    __shared__ float Bs[512 * 11];
    int t = threadIdx.x;
    for (int i = t; i < 512 * NCLS; i += 256) {
        int k = i / NCLS, c = i - k * NCLS;
        Bs[k * 11 + c] = B[i];
    }
    __syncthreads();
    int lane = t & 63;
    int m = blockIdx.x * 4 + (t >> 6);
    if (m >= N_NODES) return;
    float acc[NCLS];
#pragma unroll
    for (int c = 0; c < NCLS; c++) acc[c] = 0.f;
    const float* a = A + (size_t)m * HD;
#pragma unroll
    for (int j = 0; j < 8; j++) {
        float av = a[j * 64 + lane];
        const float* br = Bs + (j * 64 + lane) * 11;
#pragma unroll
        for (int c = 0; c < NCLS; c++) acc[c] += av * br[c];
    }
#pragma unroll
    for (int mo = 1; mo < 64; mo <<= 1)
#pragma unroll
        for (int c = 0; c < NCLS; c++) acc[c] += __shfl_xor(acc[c], mo);
    if (lane < NCLS) C[(size_t)m * NCLS + lane] = acc[lane];
}

__global__ void elr2_kernel(const float* __restrict__ feat, const float* __restrict__ al,
                            const float* __restrict__ ar, float* __restrict__ el,
                            float* __restrict__ er) {
    int n = blockIdx.x * blockDim.x + threadIdx.x;
    if (n >= N_NODES) return;
    float a = 0.f, b = 0.f;
    for (int c = 0; c < NCLS; c++) {
        float f = feat[n * NCLS + c];
        a += f * al[c]; b += f * ar[c];
    }
    el[n] = a; er[n] = b;
}

__global__ void agg2_kernel(const int* __restrict__ row_ptr, const int* __restrict__ src_sorted,
                            const float* __restrict__ alpha, const float* __restrict__ feat,
                            const float* __restrict__ b2, float* __restrict__ out) {
    int t = blockIdx.x * blockDim.x + threadIdx.x;
    int n = t >> 4, c = t & 15;
    if (n >= N_NODES || c >= NCLS) return;
    float acc = b2[c];
    int s0 = row_ptr[n], s1 = row_ptr[n + 1];
    for (int p = s0; p < s1; p++)
        acc += alpha[p] * feat[src_sorted[p] * NCLS + c];
    out[n * NCLS + c] = acc;  // H=1: mean over heads is identity
}

// ---------------------------------------------------------------------------
extern "C" void kernel_launch(void* const* d_in, const int* in_sizes, int n_in,
                              void* d_out, int out_size, void* d_ws, size_t ws_size,
                              hipStream_t stream) {
    const float* feat0 = (const float*)d_in[0];
    const float* feat1 = (const float*)d_in[1];
    const float* fc0_w = (const float*)d_in[2];
    const float* fc0_b = (const float*)d_in[3];
    const float* fc1_w = (const float*)d_in[4];
    const float* fc1_b = (const float*)d_in[5];
    const float* W0    = (const float*)d_in[6];
    const float* al0   = (const float*)d_in[7];
    const float* ar0   = (const float*)d_in[8];
    const float* b0    = (const float*)d_in[9];
    const float* W1    = (const float*)d_in[10];
    const float* al1   = (const float*)d_in[11];
    const float* ar1   = (const float*)d_in[12];
    const float* b1    = (const float*)d_in[13];
    const float* W2    = (const float*)d_in[14];
    const float* al2   = (const float*)d_in[15];
    const float* ar2   = (const float*)d_in[16];
    const float* b2    = (const float*)d_in[17];
    const int* eidx    = (const int*)d_in[18];
    const int* src = eidx;
    const int* dst = eidx + N_EDGES;
    float* out = (float*)d_out;

    char* ws = (char*)d_ws;
    size_t off = 0;
    auto alloc = [&](size_t bytes) { size_t o = off; off = (off + bytes + 255) & ~(size_t)255; return o; };

    __hip_bfloat16* featAbf = (__hip_bfloat16*)(ws + alloc((size_t)M_PAD * HD * 2));  // 51.2 MB
    size_t agg_off = alloc((size_t)N_NODES * HD * 4);  // region shared: aggbf then aggf32
    __hip_bfloat16* aggbf   = (__hip_bfloat16*)(ws + agg_off);   // M_PAD*HD*2 <= region
    float*          aggf32  = (float*)         (ws + agg_off);
    __hip_bfloat16* h0bf    = (__hip_bfloat16*)(ws + alloc((size_t)M_PAD * 64 * 2));
    float*          feat2   = (float*)(ws + alloc((size_t)N_NODES * NCLS * 4));
    float*          el      = (float*)(ws + alloc((size_t)N_NODES * HEADS * 4));
    float*          er      = (float*)(ws + alloc((size_t)N_NODES * HEADS * 4));
    float*          alpha   = (float*)(ws + alloc((size_t)N_EDGES * HEADS * 4));
    int*            cnt     = (int*)  (ws + alloc((size_t)N_NODES * 4));
    int*            rp      = (int*)  (ws + alloc((size_t)(N_NODES + 1) * 4));
    int*            cur     = (int*)  (ws + alloc((size_t)N_NODES * 4));
    int*            srcs    = (int*)  (ws + alloc((size_t)N_EDGES * 4));
    int*            part    = (int*)  (ws + alloc(1024));
    __hip_bfloat16* W0t     = (__hip_bfloat16*)(ws + alloc(512 * 64 * 2));
    __hip_bfloat16* W1t     = (__hip_bfloat16*)(ws + alloc(512 * 512 * 2));

    // --- fc projection via tiled fp32 GEMM, bf16+bias epilogue ---
    fc_gemm<<<dim3(1, (30000 + 63) / 64), 256, 0, stream>>>(feat0, fc0_w, fc0_b, h0bf, 30000, 256, 0);
    fc_gemm<<<dim3(1, (20000 + 63) / 64), 256, 0, stream>>>(feat1, fc1_w, fc1_b, h0bf, 20000, 128, 30000);

    // --- weight transpose+cast ---
    wtrans<<<(512 * 64 + 255) / 256, 256, 0, stream>>>(W0, W0t, 64, 512);
    wtrans<<<(512 * 512 + 255) / 256, 256, 0, stream>>>(W1, W1t, 512, 512);

    // --- CSR build ---
    hipMemsetAsync(cnt, 0, N_NODES * sizeof(int), stream);
    count_kernel<<<(N_EDGES + 255) / 256, 256, 0, stream>>>(dst, cnt);
    scan_part<<<NBLK_SCAN, 256, 0, stream>>>(cnt, part);
    scan_offs<<<1, 64, 0, stream>>>(part);
    scan_apply<<<NBLK_SCAN, 256, 0, stream>>>(cnt, part, rp, cur);
    scatter_kernel<<<(N_EDGES + 255) / 256, 256, 0, stream>>>(src, dst, cur, srcs);

    dim3 ggrid(HD / 128, M_PAD / 128);  // (4, 391)

    // --- layer 0 (GEMM + fused el/er) ---
    gemm_mfma<<<ggrid, 256, 0, stream>>>((const ushort*)h0bf, (const ushort*)W0t, featAbf,
                                         al0, ar0, el, er, N_NODES, HD, 64);
    attn_kernel<<<(N_NODES * HEADS + 255) / 256, 256, 0, stream>>>(rp, srcs, el, er, alpha, HEADS);
    agg_kernel<<<(N_NODES + 3) / 4, 256, 0, stream>>>(rp, srcs, alpha, featAbf, b0, aggbf);

    // --- layer 1 ---
    gemm_mfma<<<ggrid, 256, 0, stream>>>((const ushort*)aggbf, (const ushort*)W1t, featAbf,
                                         al1, ar1, el, er, N_NODES, HD, HD);
    attn_kernel<<<(N_NODES * HEADS + 255) / 256, 256, 0, stream>>>(rp, srcs, el, er, alpha, HEADS);
    agg_kernel<<<(N_NODES + 3) / 4, 256, 0, stream>>>(rp, srcs, alpha, featAbf, b1, aggf32);

    // --- layer 2 (fp32) ---
    gemm_n10v2<<<(N_NODES + 3) / 4, 256, 0, stream>>>(aggf32, W2, feat2);
    elr2_kernel<<<(N_NODES + 255) / 256, 256, 0, stream>>>(feat2, al2, ar2, el, er);
    attn_kernel<<<(N_NODES + 255) / 256, 256, 0, stream>>>(rp, srcs, el, er, alpha, 1);
    agg2_kernel<<<(N_NODES * 16 + 255) / 256, 256, 0, stream>>>(rp, srcs, alpha, feat2, b2, out);
}

// Round 4
// 544.640 us; speedup vs baseline: 3.0477x; 1.1427x over previous
//
#include <hip/hip_runtime.h>
#include <hip/hip_bf16.h>

#define N_NODES 50000
#define N_EDGES 500000
#define HEADS 8
#define HID 64
#define HD 512   // HEADS*HID
#define NCLS 10
#define M_PAD 50048  // 391*128, GEMM M padded to tile

typedef __bf16 bf16x8 __attribute__((ext_vector_type(8)));
typedef float  f32x4  __attribute__((ext_vector_type(4)));
typedef unsigned short us8v __attribute__((ext_vector_type(8)));

__device__ __forceinline__ float bf2f(unsigned short u) {
    union { unsigned int i; float f; } v; v.i = ((unsigned int)u) << 16; return v.f;
}
__device__ __forceinline__ unsigned short f2bf(float x) {
    __hip_bfloat16 b = __float2bfloat16(x);
    return *reinterpret_cast<unsigned short*>(&b);
}

#define GLD_LDS16(g, l) __builtin_amdgcn_global_load_lds( \
    (__attribute__((address_space(1))) void*)(g),         \
    (__attribute__((address_space(3))) void*)(l), 16, 0, 0)

// ---------------------------------------------------------------------------
// fc projection, both node types in one launch: tiled fp32 GEMM 64x64, BK=16
// epilogue: +bias, bf16 store into h0bf [M_PAD x 64]
// ---------------------------------------------------------------------------
#define T0_TILES 469  // ceil(30000/64)
#define T1_TILES 313  // ceil(20000/64)
__global__ __launch_bounds__(256) void fc_gemm(const float* __restrict__ A0,
                                               const float* __restrict__ B0,
                                               const float* __restrict__ bias0,
                                               const float* __restrict__ A1,
                                               const float* __restrict__ B1,
                                               const float* __restrict__ bias1,
                                               __hip_bfloat16* __restrict__ Cb) {
    __shared__ float As[16][68];
    __shared__ float Bs[16][68];
    int bid = blockIdx.x;
    const float* A; const float* B; const float* bias;
    int M, K, row_off, m0;
    if (bid < T0_TILES) { A = A0; B = B0; bias = bias0; M = 30000; K = 256; row_off = 0;     m0 = bid * 64; }
    else                { A = A1; B = B1; bias = bias1; M = 20000; K = 128; row_off = 30000; m0 = (bid - T0_TILES) * 64; }
    int tid = threadIdx.x;
    int tx = tid & 15, ty = tid >> 4;
    float acc[4][4] = {};
    int arow = tid >> 2;
    int akq  = (tid & 3) * 4;
    int brow = tid >> 4;
    int bcol = (tid & 15) * 4;
    for (int k0 = 0; k0 < K; k0 += 16) {
        int m = m0 + arow;
        float4 av = make_float4(0.f, 0.f, 0.f, 0.f);
        if (m < M) av = *(const float4*)(A + (size_t)m * K + k0 + akq);
        As[akq + 0][arow] = av.x; As[akq + 1][arow] = av.y;
        As[akq + 2][arow] = av.z; As[akq + 3][arow] = av.w;
        float4 bv = *(const float4*)(B + (size_t)(k0 + brow) * 64 + bcol);
        *(float4*)(&Bs[brow][bcol]) = bv;
        __syncthreads();
#pragma unroll
        for (int k = 0; k < 16; k++) {
            float4 a = *(const float4*)(&As[k][ty * 4]);
            float4 b = *(const float4*)(&Bs[k][tx * 4]);
            float av4[4] = {a.x, a.y, a.z, a.w};
            float bv4[4] = {b.x, b.y, b.z, b.w};
#pragma unroll
            for (int i = 0; i < 4; i++)
#pragma unroll
                for (int j = 0; j < 4; j++) acc[i][j] += av4[i] * bv4[j];
        }
        __syncthreads();
    }
#pragma unroll
    for (int i = 0; i < 4; i++) {
        int m = m0 + ty * 4 + i;
        if (m < M) {
#pragma unroll
            for (int j = 0; j < 4; j++) {
                int col = tx * 4 + j;
                Cb[(size_t)(row_off + m) * 64 + col] = __float2bfloat16(acc[i][j] + bias[col]);
            }
        }
    }
}

// ---------------------------------------------------------------------------
// CSR build: count -> parallel scan (3 kernels) -> scatter
// ---------------------------------------------------------------------------
#define NBLK_SCAN 196  // ceil(50000/256)

__global__ void count_kernel(const int* __restrict__ dst, int* __restrict__ cnt) {
    int t = blockIdx.x * blockDim.x + threadIdx.x;
    if (t < N_EDGES) atomicAdd(&cnt[dst[t]], 1);
}

__global__ void scan_part(const int* __restrict__ cnt, int* __restrict__ part) {
    __shared__ int s[256];
    int i = blockIdx.x * 256 + threadIdx.x;
    s[threadIdx.x] = (i < N_NODES) ? cnt[i] : 0;
    __syncthreads();
    for (int off = 128; off; off >>= 1) {
        if (threadIdx.x < off) s[threadIdx.x] += s[threadIdx.x + off];
        __syncthreads();
    }
    if (threadIdx.x == 0) part[blockIdx.x] = s[0];
}

__global__ void scan_offs(int* __restrict__ part) {
    __shared__ int s[256];
    int tid = threadIdx.x;
    int v = (tid < NBLK_SCAN) ? part[tid] : 0;
    s[tid] = v;
    __syncthreads();
    for (int off = 1; off < 256; off <<= 1) {
        int x = (tid >= off) ? s[tid - off] : 0;
        __syncthreads();
        s[tid] += x;
        __syncthreads();
    }
    if (tid < NBLK_SCAN) part[tid] = s[tid] - v;  // exclusive
}

__global__ void scan_apply(const int* __restrict__ cnt, const int* __restrict__ part,
                           int* __restrict__ rp, int* __restrict__ cur) {
    __shared__ int s[256];
    int tid = threadIdx.x;
    int i = blockIdx.x * 256 + tid;
    int v = (i < N_NODES) ? cnt[i] : 0;
    s[tid] = v;
    __syncthreads();
    for (int off = 1; off < 256; off <<= 1) {
        int x = (tid >= off) ? s[tid - off] : 0;
        __syncthreads();
        s[tid] += x;
        __syncthreads();
    }
    if (i < N_NODES) {
        int excl = s[tid] - v + part[blockIdx.x];
        rp[i] = excl; cur[i] = excl;
    }
    if (i == 0) rp[N_NODES] = N_EDGES;
}

__global__ void scatter_kernel(const int* __restrict__ src, const int* __restrict__ dst,
                               int* __restrict__ cursor, int* __restrict__ src_sorted) {
    int t = blockIdx.x * blockDim.x + threadIdx.x;
    if (t >= N_EDGES) return;
    int pos = atomicAdd(&cursor[dst[t]], 1);
    src_sorted[pos] = src[t];
}

// ---------------------------------------------------------------------------
// weight transpose+cast: Wt[n][k] = bf16(W[k][n])
// ---------------------------------------------------------------------------
__global__ void wtrans(const float* __restrict__ W, __hip_bfloat16* __restrict__ Wt,
                       int Kdim, int Ndim) {
    int t = blockIdx.x * blockDim.x + threadIdx.x;
    if (t >= Kdim * Ndim) return;
    int n = t / Kdim, k = t - n * Kdim;
    Wt[t] = __float2bfloat16(W[k * Ndim + n]);
}

// ---------------------------------------------------------------------------
// bf16 MFMA GEMM: Cb[M,N]bf16 = A[M_pad,K]bf16 @ Bt[N,K]bf16^T
// 128x128 tile, BK=32, 4 waves, 4x4 16x16x32 MFMAs per wave.
// Fused epilogue: el[n,h] = sum_d C[n,h*64+d]*al[h*64+d] (each wave = 1 head).
// ---------------------------------------------------------------------------
__global__ __launch_bounds__(256) void gemm_mfma(const ushort* __restrict__ A,
                                                 const ushort* __restrict__ Bt,
                                                 __hip_bfloat16* __restrict__ Cb,
                                                 const float* __restrict__ al,
                                                 const float* __restrict__ ar,
                                                 float* __restrict__ el,
                                                 float* __restrict__ er,
                                                 int M, int N, int K) {
    __shared__ ushort Asl[128 * 32];
    __shared__ ushort Bsl[128 * 32];
    int t = threadIdx.x;
    int m0 = blockIdx.y * 128, n0 = blockIdx.x * 128;
    int lane = t & 63;
    int w = t >> 6;
    int wm = (w & 1) * 64, wn = (w >> 1) * 64;
    int l15 = lane & 15, quad = lane >> 4;
    f32x4 acc[4][4];
#pragma unroll
    for (int i = 0; i < 4; i++)
#pragma unroll
        for (int j = 0; j < 4; j++) acc[i][j] = (f32x4){0.f, 0.f, 0.f, 0.f};

    int fb0 = t * 16;
    int fb1 = fb0 + 4096;
    int row0 = fb0 >> 6, kg0 = ((fb0 >> 4) & 3) ^ (row0 & 3);
    int row1 = fb1 >> 6, kg1 = ((fb1 >> 4) & 3) ^ (row1 & 3);

    for (int k0 = 0; k0 < K; k0 += 32) {
        GLD_LDS16(A + (size_t)(m0 + row0) * K + k0 + kg0 * 8, (char*)Asl + fb0);
        GLD_LDS16(A + (size_t)(m0 + row1) * K + k0 + kg1 * 8, (char*)Asl + fb1);
        GLD_LDS16(Bt + (size_t)(n0 + row0) * K + k0 + kg0 * 8, (char*)Bsl + fb0);
        GLD_LDS16(Bt + (size_t)(n0 + row1) * K + k0 + kg1 * 8, (char*)Bsl + fb1);
        __syncthreads();
        bf16x8 af[4], bfr[4];
#pragma unroll
        for (int i = 0; i < 4; i++) {
            int r = wm + i * 16 + l15;
            int kg = quad ^ (r & 3);
            af[i] = *(const bf16x8*)(Asl + r * 32 + kg * 8);
        }
#pragma unroll
        for (int j = 0; j < 4; j++) {
            int r = wn + j * 16 + l15;
            int kg = quad ^ (r & 3);
            bfr[j] = *(const bf16x8*)(Bsl + r * 32 + kg * 8);
        }
#pragma unroll
        for (int i = 0; i < 4; i++)
#pragma unroll
            for (int j = 0; j < 4; j++)
                acc[i][j] = __builtin_amdgcn_mfma_f32_16x16x32_bf16(af[i], bfr[j], acc[i][j], 0, 0, 0);
        __syncthreads();
    }
    // C/D layout: col = l15, row = quad*4 + reg  [m89/m91 verified]
#pragma unroll
    for (int i = 0; i < 4; i++) {
        int rbase = m0 + wm + i * 16 + quad * 4;
#pragma unroll
        for (int j = 0; j < 4; j++) {
            int col = n0 + wn + j * 16 + l15;
#pragma unroll
            for (int r = 0; r < 4; r++) {
                int row = rbase + r;
                if (row < M) Cb[(size_t)row * N + col] = __float2bfloat16(acc[i][j][r]);
            }
        }
    }
    // fused el/er: this wave's 64 cols = head h, exactly
    int h = (n0 + wn) >> 6;
    float alv[4], arv[4];
#pragma unroll
    for (int j = 0; j < 4; j++) {
        alv[j] = al[h * 64 + j * 16 + l15];
        arv[j] = ar[h * 64 + j * 16 + l15];
    }
#pragma unroll
    for (int i = 0; i < 4; i++) {
#pragma unroll
        for (int r = 0; r < 4; r++) {
            float sl = 0.f, sr = 0.f;
#pragma unroll
            for (int j = 0; j < 4; j++) {
                float v = acc[i][j][r];
                sl += v * alv[j]; sr += v * arv[j];
            }
#pragma unroll
            for (int mk = 1; mk < 16; mk <<= 1) {
                sl += __shfl_xor(sl, mk);
                sr += __shfl_xor(sr, mk);
            }
            int row = m0 + wm + i * 16 + quad * 4 + r;
            if (l15 == 0 && row < M) {
                el[row * HEADS + h] = sl;
                er[row * HEADS + h] = sr;
            }
        }
    }
}

// ---------------------------------------------------------------------------
// Fused edge softmax + aggregation, wave per dst node.
// Phase A (lanes=edges): gather el, leaky, shuffle max/sum, alpha -> LDS.
// Phase B (lanes=dims):  one dwordx4 per edge fetches the full 1KB row.
// out = elu(sum alpha*feat[src] + bias), bf16.
// ---------------------------------------------------------------------------
__global__ __launch_bounds__(256) void attn_agg(
        const int* __restrict__ rp, const int* __restrict__ srcs,
        const float* __restrict__ el, const float* __restrict__ er,
        const ushort* __restrict__ feat, const float* __restrict__ bias,
        ushort* __restrict__ out) {
    __shared__ float aS[4][592];   // [0..575] alpha (p*9+h), [576..583] inv, [584..591] m
    __shared__ int   sS[4][64];
    int lane = threadIdx.x & 63;
    int w    = threadIdx.x >> 6;
    int n    = blockIdx.x * 4 + w;
    int s0 = rp[n], s1 = rp[n + 1];
    int deg = s1 - s0;
    float er8[8];
    {
        f32x4 a = *(const f32x4*)(er + (size_t)n * 8);
        f32x4 b = *(const f32x4*)(er + (size_t)n * 8 + 4);
        er8[0]=a[0]; er8[1]=a[1]; er8[2]=a[2]; er8[3]=a[3];
        er8[4]=b[0]; er8[5]=b[1]; er8[6]=b[2]; er8[7]=b[3];
    }
    bool fast = (deg <= 64);
    if (fast) {
        bool act = lane < deg;
        int sp = act ? srcs[s0 + lane] : 0;
        sS[w][lane] = sp;
        f32x4 ea = {0.f,0.f,0.f,0.f}, eb = {0.f,0.f,0.f,0.f};
        if (act) {
            ea = *(const f32x4*)(el + (size_t)sp * 8);
            eb = *(const f32x4*)(el + (size_t)sp * 8 + 4);
        }
        float e8[8] = {ea[0],ea[1],ea[2],ea[3],eb[0],eb[1],eb[2],eb[3]};
        float m8[8], s8[8];
#pragma unroll
        for (int h = 0; h < 8; h++) {
            float e = e8[h] + er8[h];
            e = e > 0.f ? e : 0.2f * e;
            e8[h] = act ? e : -1e30f;
        }
#pragma unroll
        for (int h = 0; h < 8; h++) {
            float mm = e8[h];
#pragma unroll
            for (int mk = 1; mk < 64; mk <<= 1) mm = fmaxf(mm, __shfl_xor(mm, mk));
            m8[h] = mm;
        }
#pragma unroll
        for (int h = 0; h < 8; h++) {
            float pv = act ? __expf(e8[h] - m8[h]) : 0.f;
            aS[w][lane * 9 + h] = pv;
            float ss = pv;
#pragma unroll
            for (int mk = 1; mk < 64; mk <<= 1) ss += __shfl_xor(ss, mk);
            s8[h] = ss;
        }
        if (lane == 0) {
#pragma unroll
            for (int h = 0; h < 8; h++) aS[w][576 + h] = 1.f / fmaxf(s8[h], 1e-9f);
        }
    } else {
        float m8[8], s8[8];
#pragma unroll
        for (int h = 0; h < 8; h++) { m8[h] = -1e30f; s8[h] = 0.f; }
        for (int base = s0; base < s1; base += 64) {
            bool act = base + lane < s1;
            int sp = act ? srcs[base + lane] : 0;
            f32x4 ea = {0.f,0.f,0.f,0.f}, eb = {0.f,0.f,0.f,0.f};
            if (act) {
                ea = *(const f32x4*)(el + (size_t)sp * 8);
                eb = *(const f32x4*)(el + (size_t)sp * 8 + 4);
            }
            float ev[8] = {ea[0],ea[1],ea[2],ea[3],eb[0],eb[1],eb[2],eb[3]};
#pragma unroll
            for (int h = 0; h < 8; h++) {
                float e = ev[h] + er8[h];
                e = e > 0.f ? e : 0.2f * e;
                e = act ? e : -1e30f;
                float cm = e;
#pragma unroll
                for (int mk = 1; mk < 64; mk <<= 1) cm = fmaxf(cm, __shfl_xor(cm, mk));
                float nm = fmaxf(m8[h], cm);
                float pv = act ? __expf(e - nm) : 0.f;
#pragma unroll
                for (int mk = 1; mk < 64; mk <<= 1) pv += __shfl_xor(pv, mk);
                s8[h] = s8[h] * __expf(m8[h] - nm) + pv;
                m8[h] = nm;
            }
        }
        if (lane == 0) {
#pragma unroll
            for (int h = 0; h < 8; h++) {
                aS[w][576 + h] = 1.f / fmaxf(s8[h], 1e-9f);
                aS[w][584 + h] = m8[h];
            }
        }
    }
    __syncthreads();
    int hh = lane >> 3, d0 = (lane & 7) * 8;   // lane*8 = hh*64 + d0
    float inv_l = aS[w][576 + hh];
    float acc[8] = {0.f,0.f,0.f,0.f,0.f,0.f,0.f,0.f};
    const ushort* colbase = feat + hh * 64 + d0;
    if (fast) {
        for (int p = 0; p < deg; p++) {
            int sp = sS[w][p];
            float a = aS[w][p * 9 + hh] * inv_l;
            us8v f = *(const us8v*)(colbase + (size_t)sp * HD);
#pragma unroll
            for (int j = 0; j < 8; j++) acc[j] += a * bf2f(f[j]);
        }
    } else {
        float m_l   = aS[w][584 + hh];
        float ern_l = er[(size_t)n * 8 + hh];
        for (int p = s0; p < s1; p++) {
            int sp = srcs[p];
            float e = el[(size_t)sp * 8 + hh] + ern_l;
            e = e > 0.f ? e : 0.2f * e;
            float a = __expf(e - m_l) * inv_l;
            us8v f = *(const us8v*)(colbase + (size_t)sp * HD);
#pragma unroll
            for (int j = 0; j < 8; j++) acc[j] += a * bf2f(f[j]);
        }
    }
    float4 b0v = *(const float4*)(bias + lane * 8);
    float4 b1v = *(const float4*)(bias + lane * 8 + 4);
    float bb[8] = {b0v.x,b0v.y,b0v.z,b0v.w,b1v.x,b1v.y,b1v.z,b1v.w};
    us8v o;
#pragma unroll
    for (int j = 0; j < 8; j++) {
        float x = acc[j] + bb[j];
        x = x > 0.f ? x : __expf(x) - 1.f;
        o[j] = f2bf(x);
    }
    *(us8v*)(out + (size_t)n * HD + lane * 8) = o;
}

// ---------------------------------------------------------------------------
// layer 2 GEMM (N=10) from bf16 A, fused el2/er2 epilogue
// ---------------------------------------------------------------------------
__global__ __launch_bounds__(256) void gemm_n10v2(
        const ushort* __restrict__ A, const float* __restrict__ B,
        const float* __restrict__ al2, const float* __restrict__ ar2,
        float* __restrict__ C, float* __restrict__ el, float* __restrict__ er) {
    __shared__ float Bs[512 * 11];
    int t = threadIdx.x;
    for (int i = t; i < 512 * NCLS; i += 256) {
        int k = i / NCLS, c = i - k * NCLS;
        Bs[k * 11 + c] = B[i];
    }
    __syncthreads();
    int lane = t & 63;
    int m = blockIdx.x * 4 + (t >> 6);
    float acc[NCLS];
#pragma unroll
    for (int c = 0; c < NCLS; c++) acc[c] = 0.f;
    const ushort* a = A + (size_t)m * HD;
#pragma unroll
    for (int j = 0; j < 8; j++) {
        float av = bf2f(a[j * 64 + lane]);
        const float* br = Bs + (j * 64 + lane) * 11;
#pragma unroll
        for (int c = 0; c < NCLS; c++) acc[c] += av * br[c];
    }
#pragma unroll
    for (int c = 0; c < NCLS; c++)
#pragma unroll
        for (int mk = 1; mk < 64; mk <<= 1) acc[c] += __shfl_xor(acc[c], mk);
    if (lane == 0) {
        float e1 = 0.f, e2 = 0.f;
#pragma unroll
        for (int c = 0; c < NCLS; c++) { e1 += acc[c] * al2[c]; e2 += acc[c] * ar2[c]; }
        el[m] = e1; er[m] = e2;
#pragma unroll
        for (int c = 0; c < NCLS; c++) C[(size_t)m * NCLS + c] = acc[c];
    }
}

// ---------------------------------------------------------------------------
// layer 2 fused softmax+aggregation (H=1, D=10), wave per dst node
// ---------------------------------------------------------------------------
__global__ __launch_bounds__(256) void attn2_agg2(
        const int* __restrict__ rp, const int* __restrict__ srcs,
        const float* __restrict__ el, const float* __restrict__ er,
        const float* __restrict__ feat2, const float* __restrict__ b2,
        float* __restrict__ out) {
    int lane = threadIdx.x & 63;
    int n = blockIdx.x * 4 + (threadIdx.x >> 6);
    int s0 = rp[n], s1 = rp[n + 1], deg = s1 - s0;
    float ern = er[n];
    float facc[NCLS];
#pragma unroll
    for (int c = 0; c < NCLS; c++) facc[c] = 0.f;
    if (deg <= 64) {
        bool act = lane < deg;
        int sp = act ? srcs[s0 + lane] : 0;
        float e = act ? el[sp] + ern : 0.f;
        e = e > 0.f ? e : 0.2f * e;
        if (!act) e = -1e30f;
        float mm = e;
#pragma unroll
        for (int mk = 1; mk < 64; mk <<= 1) mm = fmaxf(mm, __shfl_xor(mm, mk));
        float pv = act ? __expf(e - mm) : 0.f;
        float ss = pv;
#pragma unroll
        for (int mk = 1; mk < 64; mk <<= 1) ss += __shfl_xor(ss, mk);
        float a = pv / fmaxf(ss, 1e-9f);
        if (act) {
#pragma unroll
            for (int c = 0; c < NCLS; c++) facc[c] = a * feat2[(size_t)sp * NCLS + c];
        }
    } else {
        float mm = -1e30f, ssum = 0.f;
        for (int base = s0; base < s1; base += 64) {
            bool act = base + lane < s1;
            int sp = act ? srcs[base + lane] : 0;
            float e = act ? el[sp] + ern : 0.f;
            e = e > 0.f ? e : 0.2f * e;
            if (!act) e = -1e30f;
            float cm = e;
#pragma unroll
            for (int mk = 1; mk < 64; mk <<= 1) cm = fmaxf(cm, __shfl_xor(cm, mk));
            float nm = fmaxf(mm, cm);
            float pv = act ? __expf(e - nm) : 0.f;
#pragma unroll
            for (int mk = 1; mk < 64; mk <<= 1) pv += __shfl_xor(pv, mk);
            ssum = ssum * __expf(mm - nm) + pv;
            mm = nm;
        }
        float inv = 1.f / fmaxf(ssum, 1e-9f);
        for (int base = s0; base < s1; base += 64) {
            bool act = base + lane < s1;
            int sp = act ? srcs[base + lane] : 0;
            float e = act ? el[sp] + ern : 0.f;
            e = e > 0.f ? e : 0.2f * e;
            float a = act ? __expf(e - mm) * inv : 0.f;
            if (act) {
#pragma unroll
                for (int c = 0; c < NCLS; c++) facc[c] += a * feat2[(size_t)sp * NCLS + c];
            }
        }
    }
#pragma unroll
    for (int c = 0; c < NCLS; c++)
#pragma unroll
        for (int mk = 1; mk < 64; mk <<= 1) facc[c] += __shfl_xor(facc[c], mk);
    if (lane == 0) {
#pragma unroll
        for (int c = 0; c < NCLS; c++) out[(size_t)n * NCLS + c] = facc[c] + b2[c];
    }
}

// ---------------------------------------------------------------------------
extern "C" void kernel_launch(void* const* d_in, const int* in_sizes, int n_in,
                              void* d_out, int out_size, void* d_ws, size_t ws_size,
                              hipStream_t stream) {
    const float* feat0 = (const float*)d_in[0];
    const float* feat1 = (const float*)d_in[1];
    const float* fc0_w = (const float*)d_in[2];
    const float* fc0_b = (const float*)d_in[3];
    const float* fc1_w = (const float*)d_in[4];
    const float* fc1_b = (const float*)d_in[5];
    const float* W0    = (const float*)d_in[6];
    const float* al0   = (const float*)d_in[7];
    const float* ar0   = (const float*)d_in[8];
    const float* b0    = (const float*)d_in[9];
    const float* W1    = (const float*)d_in[10];
    const float* al1   = (const float*)d_in[11];
    const float* ar1   = (const float*)d_in[12];
    const float* b1    = (const float*)d_in[13];
    const float* W2    = (const float*)d_in[14];
    const float* al2   = (const float*)d_in[15];
    const float* ar2   = (const float*)d_in[16];
    const float* b2    = (const float*)d_in[17];
    const int* eidx    = (const int*)d_in[18];
    const int* src = eidx;
    const int* dst = eidx + N_EDGES;
    float* out = (float*)d_out;

    char* ws = (char*)d_ws;
    size_t off = 0;
    auto alloc = [&](size_t bytes) { size_t o = off; off = (off + bytes + 255) & ~(size_t)255; return o; };

    __hip_bfloat16* featAbf = (__hip_bfloat16*)(ws + alloc((size_t)M_PAD * HD * 2));
    __hip_bfloat16* aggbf   = (__hip_bfloat16*)(ws + alloc((size_t)M_PAD * HD * 2));
    __hip_bfloat16* h0bf    = (__hip_bfloat16*)(ws + alloc((size_t)M_PAD * 64 * 2));
    float*          feat2   = (float*)(ws + alloc((size_t)N_NODES * NCLS * 4));
    float*          el      = (float*)(ws + alloc((size_t)N_NODES * HEADS * 4));
    float*          er      = (float*)(ws + alloc((size_t)N_NODES * HEADS * 4));
    int*            cnt     = (int*)  (ws + alloc((size_t)N_NODES * 4));
    int*            rp      = (int*)  (ws + alloc((size_t)(N_NODES + 1) * 4));
    int*            cur     = (int*)  (ws + alloc((size_t)N_NODES * 4));
    int*            srcs    = (int*)  (ws + alloc((size_t)N_EDGES * 4));
    int*            part    = (int*)  (ws + alloc(1024));
    __hip_bfloat16* W0t     = (__hip_bfloat16*)(ws + alloc(512 * 64 * 2));
    __hip_bfloat16* W1t     = (__hip_bfloat16*)(ws + alloc(512 * 512 * 2));

    // --- fc projection (both types, one launch) ---
    fc_gemm<<<T0_TILES + T1_TILES, 256, 0, stream>>>(feat0, fc0_w, fc0_b,
                                                     feat1, fc1_w, fc1_b, h0bf);
    // --- weight transpose+cast ---
    wtrans<<<(512 * 64 + 255) / 256, 256, 0, stream>>>(W0, W0t, 64, 512);
    wtrans<<<(512 * 512 + 255) / 256, 256, 0, stream>>>(W1, W1t, 512, 512);

    // --- CSR build ---
    hipMemsetAsync(cnt, 0, N_NODES * sizeof(int), stream);
    count_kernel<<<(N_EDGES + 255) / 256, 256, 0, stream>>>(dst, cnt);
    scan_part<<<NBLK_SCAN, 256, 0, stream>>>(cnt, part);
    scan_offs<<<1, 256, 0, stream>>>(part);
    scan_apply<<<NBLK_SCAN, 256, 0, stream>>>(cnt, part, rp, cur);
    scatter_kernel<<<(N_EDGES + 255) / 256, 256, 0, stream>>>(src, dst, cur, srcs);

    dim3 ggrid(HD / 128, M_PAD / 128);  // (4, 391)

    // --- layer 0 ---
    gemm_mfma<<<ggrid, 256, 0, stream>>>((const ushort*)h0bf, (const ushort*)W0t, featAbf,
                                         al0, ar0, el, er, N_NODES, HD, 64);
    attn_agg<<<N_NODES / 4, 256, 0, stream>>>(rp, srcs, el, er, (const ushort*)featAbf,
                                              b0, (ushort*)aggbf);

    // --- layer 1 ---
    gemm_mfma<<<ggrid, 256, 0, stream>>>((const ushort*)aggbf, (const ushort*)W1t, featAbf,
                                         al1, ar1, el, er, N_NODES, HD, HD);
    attn_agg<<<N_NODES / 4, 256, 0, stream>>>(rp, srcs, el, er, (const ushort*)featAbf,
                                              b1, (ushort*)aggbf);

    // --- layer 2 ---
    gemm_n10v2<<<N_NODES / 4, 256, 0, stream>>>((const ushort*)aggbf, W2, al2, ar2,
                                                feat2, el, er);
    attn2_agg2<<<N_NODES / 4, 256, 0, stream>>>(rp, srcs, el, er, feat2, b2, out);
}